// Round 1
// baseline (610.564 us; speedup 1.0000x reference)
//
#include <hip/hip_runtime.h>
#include <cstdint>

#define HH 76
#define WW 128
#define AA 9
#define HWH (HH * WW)          // 9728
#define KK (HWH * AA)          // 87552
#define NSEL 6000
#define NCH 94                 // ceil(6000/64)
#define NPAD (NCH * 64)        // 6016
#define NOUT 1000
#define CAP 8192
#define NMS_T 0.7

// ---- workspace layout (bytes) ----
// hist      : 0        u32[65536]   (262144)
// counter   : 262144   u32
// binB      : 262148   u32
// selKeys   : 262160   u64[8192]    (65536)
// selIdx    : 327696   u32[6000]    (24000)
// boxes     : 351696   float4[6016] (96256)   (16-aligned)
// mask      : 447952   u64[6016*94] (4524032)
#define WS_HIST 0
#define WS_COUNTER 262144
#define WS_BINB 262148
#define WS_SELKEYS 262160
#define WS_SELIDX 327696
#define WS_BOXES 351696
#define WS_MASK 447952

// base anchors from generate_anchors() (numpy fp64, exact small values)
__device__ __constant__ float c_ax1[9] = {-84.f, -176.f, -360.f, -56.f, -120.f, -248.f, -36.f, -80.f, -168.f};
__device__ __constant__ float c_ay1[9] = {-40.f, -88.f, -184.f, -56.f, -120.f, -248.f, -80.f, -168.f, -344.f};
__device__ __constant__ float c_ax2[9] = {99.f, 191.f, 375.f, 71.f, 135.f, 263.f, 51.f, 95.f, 183.f};
__device__ __constant__ float c_ay2[9] = {55.f, 103.f, 199.f, 71.f, 135.f, 263.f, 95.f, 183.f, 359.f};

__device__ __forceinline__ unsigned score_key(float s) {
    unsigned u = __float_as_uint(s);
    return (u & 0x80000000u) ? ~u : (u | 0x80000000u);
}

__device__ __forceinline__ unsigned long long shfl64(unsigned long long v, int lane) {
    int lo = __shfl((int)(unsigned)(v & 0xFFFFFFFFull), lane, 64);
    int hi = __shfl((int)(unsigned)(v >> 32), lane, 64);
    return ((unsigned long long)(unsigned)hi << 32) | (unsigned)lo;
}

// 1) histogram over top-16 bits of orderable score key
__global__ void k_hist(const float* __restrict__ scores, unsigned* __restrict__ hist) {
    int i = blockIdx.x * blockDim.x + threadIdx.x;
    if (i >= KK) return;
    int a = i % AA;
    int hw = i / AA;
    int h = hw >> 7;
    int w = hw & 127;
    float s = scores[(AA + a) * HWH + h * WW + w];
    atomicAdd(&hist[score_key(s) >> 16], 1u);
}

// 2) find largest bin B with count(key>>16 >= B) >= NSEL
__global__ __launch_bounds__(1024) void k_findbin(const unsigned* __restrict__ hist,
                                                  unsigned* __restrict__ binB) {
    __shared__ unsigned seg[1024];
    int t = threadIdx.x;
    unsigned s = 0;
    for (int k = 0; k < 64; ++k) s += hist[t * 64 + k];
    seg[t] = s;
    __syncthreads();
    if (t == 0) {
        unsigned acc = 0;
        int sIdx = 1023;
        for (; sIdx > 0; --sIdx) {
            if (acc + seg[sIdx] >= NSEL) break;
            acc += seg[sIdx];
        }
        unsigned B = 0;
        for (int b = sIdx * 64 + 63; b >= sIdx * 64; --b) {
            acc += hist[b];
            if (acc >= NSEL) { B = (unsigned)b; break; }
        }
        *binB = B;
    }
}

// 3) gather candidates (key>>16 >= B) as packed u64 (key desc, idx asc)
__global__ void k_gather(const float* __restrict__ scores, const unsigned* __restrict__ binB,
                         unsigned* __restrict__ counter, unsigned long long* __restrict__ selKeys) {
    int i = blockIdx.x * blockDim.x + threadIdx.x;
    if (i >= KK) return;
    int a = i % AA;
    int hw = i / AA;
    int h = hw >> 7;
    int w = hw & 127;
    float s = scores[(AA + a) * HWH + h * WW + w];
    unsigned key = score_key(s);
    if ((key >> 16) >= *binB) {
        unsigned pos = atomicAdd(counter, 1u);
        if (pos < CAP)
            selKeys[pos] = ((unsigned long long)key << 32) | (unsigned)(~(unsigned)i);
    }
}

// 4) one-block bitonic sort (descending) of 8192 u64; emit top-6000 indices
__global__ __launch_bounds__(1024) void k_sort(const unsigned* __restrict__ counter,
                                               const unsigned long long* __restrict__ selKeys,
                                               unsigned* __restrict__ selIdx) {
    __shared__ unsigned long long sk[CAP];
    int t = threadIdx.x;
    unsigned cnt = *counter;
    if (cnt > CAP) cnt = CAP;
    for (int p = t; p < CAP; p += 1024) sk[p] = (p < (int)cnt) ? selKeys[p] : 0ull;
    __syncthreads();
    for (unsigned size = 2; size <= CAP; size <<= 1) {
        for (unsigned stride = size >> 1; stride > 0; stride >>= 1) {
            for (unsigned p = (unsigned)t; p < CAP / 2; p += 1024) {
                unsigned i = 2u * p - (p & (stride - 1u));
                unsigned j = i + stride;
                bool up = (i & size) != 0;  // ascending region
                unsigned long long a = sk[i], b = sk[j];
                bool doswap = up ? (a > b) : (a < b);  // overall descending
                if (doswap) { sk[i] = b; sk[j] = a; }
            }
            __syncthreads();
        }
    }
    for (int p = t; p < NSEL; p += 1024)
        selIdx[p] = ~(unsigned)(sk[p] & 0xFFFFFFFFull);
}

// 5) decode+clip top-6000 boxes in fp64, store fp32
__global__ void k_decode(const float* __restrict__ bbox, const float* __restrict__ im_info,
                         const unsigned* __restrict__ selIdx, float4* __restrict__ boxes) {
    int r = blockIdx.x * blockDim.x + threadIdx.x;
    if (r >= NSEL) return;
    unsigned i = selIdx[r];
    int a = (int)(i % AA);
    int hw = (int)(i / AA);
    int h = hw >> 7;
    int w = hw & 127;
    double sx = 16.0 * w, sy = 16.0 * h;
    double ax1 = (double)c_ax1[a] + sx, ay1 = (double)c_ay1[a] + sy;
    double ax2 = (double)c_ax2[a] + sx, ay2 = (double)c_ay2[a] + sy;
    double aw = ax2 - ax1 + 1.0, ah = ay2 - ay1 + 1.0;
    double acx = ax1 + 0.5 * aw, acy = ay1 + 0.5 * ah;
    int base = h * WW + w;
    double d0 = (double)bbox[(4 * a + 0) * HWH + base];
    double d1 = (double)bbox[(4 * a + 1) * HWH + base];
    double d2 = (double)bbox[(4 * a + 2) * HWH + base];
    double d3 = (double)bbox[(4 * a + 3) * HWH + base];
    double pcx = d0 * aw + acx, pcy = d1 * ah + acy;
    double pw = exp(d2) * aw, ph = exp(d3) * ah;
    double xmax = (double)im_info[1] - 1.0, ymax = (double)im_info[0] - 1.0;
    double x1 = fmin(fmax(pcx - 0.5 * pw, 0.0), xmax);
    double y1 = fmin(fmax(pcy - 0.5 * ph, 0.0), ymax);
    double x2 = fmin(fmax(pcx + 0.5 * pw, 0.0), xmax);
    double y2 = fmin(fmax(pcy + 0.5 * ph, 0.0), ymax);
    boxes[r] = make_float4((float)x1, (float)y1, (float)x2, (float)y2);
}

// 6) suppression bitmask: mask[i][cc] bit j = (iou(i, cc*64+j) > 0.7 && cc*64+j > i)
__global__ __launch_bounds__(64) void k_mask(const float4* __restrict__ boxes,
                                             unsigned long long* __restrict__ mask) {
    int rc = blockIdx.y, cc = blockIdx.x;
    if (cc < rc) return;
    __shared__ float4 cb[64];
    int t = threadIdx.x;
    cb[t] = boxes[cc * 64 + t];
    __syncthreads();
    int gi = rc * 64 + t;
    if (gi >= NSEL) return;
    float4 rb = boxes[gi];
    double rx1 = rb.x, ry1 = rb.y, rx2 = rb.z, ry2 = rb.w;
    double rarea = (rx2 - rx1 + 1.0) * (ry2 - ry1 + 1.0);
    unsigned long long bits = 0ull;
    for (int j = 0; j < 64; ++j) {
        int gj = cc * 64 + j;
        float4 c = cb[j];
        double iw = fmin(rx2, (double)c.z) - fmax(rx1, (double)c.x) + 1.0;
        double ih = fmin(ry2, (double)c.w) - fmax(ry1, (double)c.y) + 1.0;
        if (gj > gi && gj < NSEL && iw > 0.0 && ih > 0.0) {
            double inter = iw * ih;
            double carea = ((double)c.z - (double)c.x + 1.0) * ((double)c.w - (double)c.y + 1.0);
            double uni = rarea + carea - inter;
            if (inter > NMS_T * uni) bits |= (1ull << j);
        }
    }
    mask[(size_t)gi * NCH + cc] = bits;
}

// 7) sequential greedy NMS reduce (chunked) + stable compaction + output
__global__ __launch_bounds__(1024) void k_nms(const unsigned long long* __restrict__ mask,
                                              const float4* __restrict__ boxes,
                                              float4* __restrict__ out) {
    __shared__ unsigned long long removed[NCH];
    __shared__ unsigned keptList[64];
    __shared__ unsigned nkS;
    __shared__ unsigned scanBuf[1024];
    int t = threadIdx.x;
    if (t < NCH) removed[t] = 0ull;
    if (t == NCH - 1) removed[NCH - 1] = 0xFFFF000000000000ull;  // pad rows 6000..6015 dead
    __syncthreads();

    for (int c = 0; c < NCH; ++c) {
        if (t < 64) {
            unsigned long long m = mask[(size_t)(c * 64 + t) * NCH + c];  // diag word
            unsigned long long alive = ~removed[c];
            unsigned long long rest = alive;
            while (rest) {
                int i = __ffsll((long long)rest) - 1;
                unsigned long long mi = shfl64(m, i);
                alive &= ~mi;
                rest &= ~mi;
                rest &= rest - 1;  // clear bit i
            }
            if (t == 0) { removed[c] = ~alive; nkS = (unsigned)__popcll(alive); }
            if ((alive >> t) & 1ull) {
                int pos = (int)__popcll(alive & ((1ull << t) - 1ull));
                keptList[pos] = (unsigned)(c * 64 + t);
            }
        }
        __syncthreads();
        int nk = (int)nkS;
        int W2 = NCH - 1 - c;
        int total = nk * W2;
        for (int p = t; p < total; p += 1024) {
            int k = p / W2;
            int w = c + 1 + (p - k * W2);
            unsigned long long v = mask[(size_t)keptList[k] * NCH + w];
            if (v) {
                unsigned* rp = (unsigned*)&removed[w];
                unsigned lo = (unsigned)(v & 0xFFFFFFFFull);
                unsigned hi = (unsigned)(v >> 32);
                if (lo) atomicOr(&rp[0], lo);
                if (hi) atomicOr(&rp[1], hi);
            }
        }
        __syncthreads();
    }

    // stable compaction: kept (index asc) then suppressed (index asc), take first 1000
    int base = t * 6;
    unsigned cnt = 0, keepbits = 0;
    for (int q = 0; q < 6; ++q) {
        int i = base + q;
        if (i < NSEL) {
            bool kp = !((removed[i >> 6] >> (i & 63)) & 1ull);
            if (kp) { cnt++; keepbits |= (1u << q); }
        }
    }
    scanBuf[t] = cnt;
    __syncthreads();
    for (int off = 1; off < 1024; off <<= 1) {
        unsigned v = scanBuf[t];
        unsigned add = (t >= off) ? scanBuf[t - off] : 0u;
        __syncthreads();
        scanBuf[t] = v + add;
        __syncthreads();
    }
    unsigned incl = scanBuf[t];
    unsigned NK = scanBuf[1023];
    unsigned kpos = incl - cnt;  // kept-prefix at start of my range
    for (int q = 0; q < 6; ++q) {
        int i = base + q;
        if (i < NSEL) {
            bool kp = (keepbits >> q) & 1u;
            unsigned pos = kp ? kpos : (NK + (unsigned)i - kpos);
            if (kp) kpos++;
            if (pos < NOUT) out[pos] = boxes[i];
        }
    }
}

extern "C" void kernel_launch(void* const* d_in, const int* in_sizes, int n_in,
                              void* d_out, int out_size, void* d_ws, size_t ws_size,
                              hipStream_t stream) {
    const float* scores = (const float*)d_in[0];
    const float* bbox = (const float*)d_in[1];
    const float* im_info = (const float*)d_in[2];
    char* ws = (char*)d_ws;

    unsigned* hist = (unsigned*)(ws + WS_HIST);
    unsigned* counter = (unsigned*)(ws + WS_COUNTER);
    unsigned* binB = (unsigned*)(ws + WS_BINB);
    unsigned long long* selKeys = (unsigned long long*)(ws + WS_SELKEYS);
    unsigned* selIdx = (unsigned*)(ws + WS_SELIDX);
    float4* boxes = (float4*)(ws + WS_BOXES);
    unsigned long long* mask = (unsigned long long*)(ws + WS_MASK);
    float4* out = (float4*)d_out;

    // zero hist + counter + binB (re-executed every graph replay)
    hipMemsetAsync(ws, 0, WS_BINB + 4, stream);

    k_hist<<<(KK + 255) / 256, 256, 0, stream>>>(scores, hist);
    k_findbin<<<1, 1024, 0, stream>>>(hist, binB);
    k_gather<<<(KK + 255) / 256, 256, 0, stream>>>(scores, binB, counter, selKeys);
    k_sort<<<1, 1024, 0, stream>>>(counter, selKeys, selIdx);
    k_decode<<<(NSEL + 255) / 256, 256, 0, stream>>>(bbox, im_info, selIdx, boxes);
    k_mask<<<dim3(NCH, NCH), 64, 0, stream>>>(boxes, mask);
    k_nms<<<1, 1024, 0, stream>>>(mask, boxes, out);
}

// Round 2
// 453.826 us; speedup vs baseline: 1.3454x; 1.3454x over previous
//
#include <hip/hip_runtime.h>
#include <cstdint>

#define HH 76
#define WW 128
#define AA 9
#define HWH (HH * WW)          // 9728
#define KK (HWH * AA)          // 87552
#define NSEL 6000
#define NCH 94                 // ceil(6000/64)
#define NPAD (NCH * 64)        // 6016
#define NOUT 1000
#define CAP 8192
#define NMS_T 0.7
#define TILE_WORDS (64 * NCH)  // 6016 u64 per chunk-tile

// ---- workspace layout (bytes) ----
#define WS_HIST 0
#define WS_COUNTER 262144
#define WS_BINB 262148
#define WS_SELKEYS 262160
#define WS_SELIDX 327696
#define WS_BOXES 351696
#define WS_MASK 447952

// base anchors from generate_anchors() (numpy fp64, exact small values)
__device__ __constant__ float c_ax1[9] = {-84.f, -176.f, -360.f, -56.f, -120.f, -248.f, -36.f, -80.f, -168.f};
__device__ __constant__ float c_ay1[9] = {-40.f, -88.f, -184.f, -56.f, -120.f, -248.f, -80.f, -168.f, -344.f};
__device__ __constant__ float c_ax2[9] = {99.f, 191.f, 375.f, 71.f, 135.f, 263.f, 51.f, 95.f, 183.f};
__device__ __constant__ float c_ay2[9] = {55.f, 103.f, 199.f, 71.f, 135.f, 263.f, 95.f, 183.f, 359.f};

__device__ __forceinline__ unsigned score_key(float s) {
    unsigned u = __float_as_uint(s);
    return (u & 0x80000000u) ? ~u : (u | 0x80000000u);
}

// 1) histogram over top-16 bits of orderable score key
__global__ void k_hist(const float* __restrict__ scores, unsigned* __restrict__ hist) {
    int i = blockIdx.x * blockDim.x + threadIdx.x;
    if (i >= KK) return;
    int a = i % AA;
    int hw = i / AA;
    int h = hw >> 7;
    int w = hw & 127;
    float s = scores[(AA + a) * HWH + h * WW + w];
    atomicAdd(&hist[score_key(s) >> 16], 1u);
}

// 2) find largest bin B with count(key>>16 >= B) >= NSEL  (parallel suffix-scan)
__global__ __launch_bounds__(1024) void k_findbin(const unsigned* __restrict__ hist,
                                                  unsigned* __restrict__ binB) {
    __shared__ unsigned seg[1024];
    int t = threadIdx.x;
    unsigned local[64];
    unsigned s = 0;
#pragma unroll
    for (int k = 0; k < 64; ++k) { local[k] = hist[t * 64 + k]; s += local[k]; }
    seg[t] = s;
    __syncthreads();
    // inclusive suffix sum over seg
    for (int off = 1; off < 1024; off <<= 1) {
        unsigned v = seg[t];
        unsigned add = (t + off < 1024) ? seg[t + off] : 0u;
        __syncthreads();
        seg[t] = v + add;
        __syncthreads();
    }
    unsigned above = (t + 1 < 1024) ? seg[t + 1] : 0u;
    if (above < NSEL && above + s >= NSEL) {
        unsigned acc = above;
#pragma unroll
        for (int b = 63; b >= 0; --b) {
            acc += local[b];
            if (acc >= NSEL) { *binB = (unsigned)(t * 64 + b); break; }
        }
    }
}

// 3) gather candidates (key>>16 >= B) as packed u64 (key desc, idx asc)
__global__ void k_gather(const float* __restrict__ scores, const unsigned* __restrict__ binB,
                         unsigned* __restrict__ counter, unsigned long long* __restrict__ selKeys) {
    int i = blockIdx.x * blockDim.x + threadIdx.x;
    if (i >= KK) return;
    int a = i % AA;
    int hw = i / AA;
    int h = hw >> 7;
    int w = hw & 127;
    float s = scores[(AA + a) * HWH + h * WW + w];
    unsigned key = score_key(s);
    if ((key >> 16) >= *binB) {
        unsigned pos = atomicAdd(counter, 1u);
        if (pos < CAP)
            selKeys[pos] = ((unsigned long long)key << 32) | (unsigned)(~(unsigned)i);
    }
}

// 4) one-block bitonic sort (descending) of 8192 u64; emit top-6000 indices
__global__ __launch_bounds__(1024) void k_sort(const unsigned* __restrict__ counter,
                                               const unsigned long long* __restrict__ selKeys,
                                               unsigned* __restrict__ selIdx) {
    __shared__ unsigned long long sk[CAP];
    int t = threadIdx.x;
    unsigned cnt = *counter;
    if (cnt > CAP) cnt = CAP;
    for (int p = t; p < CAP; p += 1024) sk[p] = (p < (int)cnt) ? selKeys[p] : 0ull;
    __syncthreads();
    for (unsigned size = 2; size <= CAP; size <<= 1) {
        for (unsigned stride = size >> 1; stride > 0; stride >>= 1) {
            for (unsigned p = (unsigned)t; p < CAP / 2; p += 1024) {
                unsigned i = 2u * p - (p & (stride - 1u));
                unsigned j = i + stride;
                bool up = (i & size) != 0;
                unsigned long long a = sk[i], b = sk[j];
                bool doswap = up ? (a > b) : (a < b);
                if (doswap) { sk[i] = b; sk[j] = a; }
            }
            __syncthreads();
        }
    }
    for (int p = t; p < NSEL; p += 1024)
        selIdx[p] = ~(unsigned)(sk[p] & 0xFFFFFFFFull);
}

// 5) decode+clip top-6000 boxes in fp64, store fp32
__global__ void k_decode(const float* __restrict__ bbox, const float* __restrict__ im_info,
                         const unsigned* __restrict__ selIdx, float4* __restrict__ boxes) {
    int r = blockIdx.x * blockDim.x + threadIdx.x;
    if (r >= NSEL) return;
    unsigned i = selIdx[r];
    int a = (int)(i % AA);
    int hw = (int)(i / AA);
    int h = hw >> 7;
    int w = hw & 127;
    double sx = 16.0 * w, sy = 16.0 * h;
    double ax1 = (double)c_ax1[a] + sx, ay1 = (double)c_ay1[a] + sy;
    double ax2 = (double)c_ax2[a] + sx, ay2 = (double)c_ay2[a] + sy;
    double aw = ax2 - ax1 + 1.0, ah = ay2 - ay1 + 1.0;
    double acx = ax1 + 0.5 * aw, acy = ay1 + 0.5 * ah;
    int base = h * WW + w;
    double d0 = (double)bbox[(4 * a + 0) * HWH + base];
    double d1 = (double)bbox[(4 * a + 1) * HWH + base];
    double d2 = (double)bbox[(4 * a + 2) * HWH + base];
    double d3 = (double)bbox[(4 * a + 3) * HWH + base];
    double pcx = d0 * aw + acx, pcy = d1 * ah + acy;
    double pw = exp(d2) * aw, ph = exp(d3) * ah;
    double xmax = (double)im_info[1] - 1.0, ymax = (double)im_info[0] - 1.0;
    double x1 = fmin(fmax(pcx - 0.5 * pw, 0.0), xmax);
    double y1 = fmin(fmax(pcy - 0.5 * ph, 0.0), ymax);
    double x2 = fmin(fmax(pcx + 0.5 * pw, 0.0), xmax);
    double y2 = fmin(fmax(pcy + 0.5 * ph, 0.0), ymax);
    boxes[r] = make_float4((float)x1, (float)y1, (float)x2, (float)y2);
}

// 6) suppression bitmask: mask[i][cc] bit j = (iou(i, cc*64+j) > 0.7 && cc*64+j > i)
__global__ __launch_bounds__(64) void k_mask(const float4* __restrict__ boxes,
                                             unsigned long long* __restrict__ mask) {
    int rc = blockIdx.y, cc = blockIdx.x;
    if (cc < rc) return;
    __shared__ float4 cb[64];
    int t = threadIdx.x;
    cb[t] = boxes[cc * 64 + t];
    __syncthreads();
    int gi = rc * 64 + t;
    if (gi >= NSEL) return;
    float4 rb = boxes[gi];
    double rx1 = rb.x, ry1 = rb.y, rx2 = rb.z, ry2 = rb.w;
    double rarea = (rx2 - rx1 + 1.0) * (ry2 - ry1 + 1.0);
    unsigned long long bits = 0ull;
    for (int j = 0; j < 64; ++j) {
        int gj = cc * 64 + j;
        float4 c = cb[j];
        double iw = fmin(rx2, (double)c.z) - fmax(rx1, (double)c.x) + 1.0;
        double ih = fmin(ry2, (double)c.w) - fmax(ry1, (double)c.y) + 1.0;
        if (gj > gi && gj < NSEL && iw > 0.0 && ih > 0.0) {
            double inter = iw * ih;
            double carea = ((double)c.z - (double)c.x + 1.0) * ((double)c.w - (double)c.y + 1.0);
            double uni = rarea + carea - inter;
            if (inter > NMS_T * uni) bits |= (1ull << j);
        }
    }
    mask[(size_t)gi * NCH + cc] = bits;
}

// 7) greedy NMS reduce: LDS tile staging + register prefetch + scalar scan + parallel OR
__global__ __launch_bounds__(1024) void k_nms(const unsigned long long* __restrict__ mask,
                                              const float4* __restrict__ boxes,
                                              float4* __restrict__ out) {
    __shared__ unsigned long long tileF[TILE_WORDS];  // 48128 B: rows of current chunk
    __shared__ unsigned long long removed[NCH];
    __shared__ unsigned long long aliveS;
    __shared__ unsigned scanBuf[1024];
    int t = threadIdx.x;
    unsigned long long reg[6];

    // prologue: load chunk-0 tile into regs
#pragma unroll
    for (int k = 0; k < 6; ++k) {
        int f = t + k * 1024;
        reg[k] = (f < TILE_WORDS) ? mask[f] : 0ull;
    }
    if (t < NCH) removed[t] = (t == NCH - 1) ? 0xFFFF000000000000ull : 0ull;  // pad rows dead
    __syncthreads();
#pragma unroll
    for (int k = 0; k < 6; ++k) {
        int f = t + k * 1024;
        if (f < TILE_WORDS) tileF[f] = reg[k];
    }
    __syncthreads();

    for (int c = 0; c < NCH; ++c) {
        // issue prefetch of chunk c+1 (consumed at end of iteration; latency hidden)
        if (c + 1 < NCH) {
            size_t base = (size_t)(c + 1) * TILE_WORDS;
#pragma unroll
            for (int k = 0; k < 6; ++k) {
                int f = t + k * 1024;
                reg[k] = (f < TILE_WORDS) ? mask[base + f] : 0ull;
            }
        }
        // intra-chunk scan (wave 0, scalar loop via readlane)
        if (t < 64) {
            unsigned long long m = tileF[(size_t)t * NCH + c];
            unsigned mlo = (unsigned)m, mhi = (unsigned)(m >> 32);
            unsigned long long rem = removed[c];
            unsigned alo = __builtin_amdgcn_readfirstlane(~(unsigned)rem);
            unsigned ahi = __builtin_amdgcn_readfirstlane(~(unsigned)(rem >> 32));
            unsigned long long alive = ((unsigned long long)ahi << 32) | alo;
            unsigned long long rest = alive;
            while (rest) {
                int i = __ffsll((long long)rest) - 1;
                unsigned long long mi =
                    ((unsigned long long)(unsigned)__builtin_amdgcn_readlane((int)mhi, i) << 32) |
                    (unsigned)__builtin_amdgcn_readlane((int)mlo, i);
                alive &= ~mi;
                rest &= ~mi;
                rest &= rest - 1;
            }
            if (t == 0) { removed[c] = ~alive; aliveS = alive; }
        }
        __syncthreads();
        // OR phase: 8 threads per suppression word, branchless predicated LDS reads
        int W2 = NCH - 1 - c;
        if (t < W2 * 8) {
            int w = c + 1 + (t >> 3);
            int kg = (t & 7) * 8;
            unsigned long long alive = aliveS;
            unsigned long long acc = 0ull;
#pragma unroll
            for (int j = 0; j < 8; ++j) {
                int k2 = kg + j;
                unsigned long long sel = 0ull - ((alive >> k2) & 1ull);
                acc |= sel & tileF[(size_t)k2 * NCH + w];
            }
            if (acc) atomicOr(&removed[w], acc);
        }
        __syncthreads();
        // commit prefetched regs -> tile (chunk c+1)
        if (c + 1 < NCH) {
#pragma unroll
            for (int k = 0; k < 6; ++k) {
                int f = t + k * 1024;
                if (f < TILE_WORDS) tileF[f] = reg[k];
            }
        }
        __syncthreads();
    }

    // stable compaction: kept (index asc) then suppressed (index asc), take first 1000
    int base = t * 6;
    unsigned cnt = 0, keepbits = 0;
    for (int q = 0; q < 6; ++q) {
        int i = base + q;
        if (i < NSEL) {
            bool kp = !((removed[i >> 6] >> (i & 63)) & 1ull);
            if (kp) { cnt++; keepbits |= (1u << q); }
        }
    }
    scanBuf[t] = cnt;
    __syncthreads();
    for (int off = 1; off < 1024; off <<= 1) {
        unsigned v = scanBuf[t];
        unsigned add = (t >= off) ? scanBuf[t - off] : 0u;
        __syncthreads();
        scanBuf[t] = v + add;
        __syncthreads();
    }
    unsigned incl = scanBuf[t];
    unsigned NK = scanBuf[1023];
    unsigned kpos = incl - cnt;
    for (int q = 0; q < 6; ++q) {
        int i = base + q;
        if (i < NSEL) {
            bool kp = (keepbits >> q) & 1u;
            unsigned pos = kp ? kpos : (NK + (unsigned)i - kpos);
            if (kp) kpos++;
            if (pos < NOUT) out[pos] = boxes[i];
        }
    }
}

extern "C" void kernel_launch(void* const* d_in, const int* in_sizes, int n_in,
                              void* d_out, int out_size, void* d_ws, size_t ws_size,
                              hipStream_t stream) {
    const float* scores = (const float*)d_in[0];
    const float* bbox = (const float*)d_in[1];
    const float* im_info = (const float*)d_in[2];
    char* ws = (char*)d_ws;

    unsigned* hist = (unsigned*)(ws + WS_HIST);
    unsigned* counter = (unsigned*)(ws + WS_COUNTER);
    unsigned* binB = (unsigned*)(ws + WS_BINB);
    unsigned long long* selKeys = (unsigned long long*)(ws + WS_SELKEYS);
    unsigned* selIdx = (unsigned*)(ws + WS_SELIDX);
    float4* boxes = (float4*)(ws + WS_BOXES);
    unsigned long long* mask = (unsigned long long*)(ws + WS_MASK);
    float4* out = (float4*)d_out;

    hipMemsetAsync(ws, 0, WS_BINB + 4, stream);

    k_hist<<<(KK + 255) / 256, 256, 0, stream>>>(scores, hist);
    k_findbin<<<1, 1024, 0, stream>>>(hist, binB);
    k_gather<<<(KK + 255) / 256, 256, 0, stream>>>(scores, binB, counter, selKeys);
    k_sort<<<1, 1024, 0, stream>>>(counter, selKeys, selIdx);
    k_decode<<<(NSEL + 255) / 256, 256, 0, stream>>>(bbox, im_info, selIdx, boxes);
    k_mask<<<dim3(NCH, NCH), 64, 0, stream>>>(boxes, mask);
    k_nms<<<1, 1024, 0, stream>>>(mask, boxes, out);
}

// Round 3
// 417.555 us; speedup vs baseline: 1.4622x; 1.0869x over previous
//
#include <hip/hip_runtime.h>
#include <cstdint>

#define HH 76
#define WW 128
#define AA 9
#define HWH (HH * WW)          // 9728
#define KK (HWH * AA)          // 87552
#define NSEL 6000
#define NCH 94                 // ceil(6000/64)
#define NPAD (NCH * 64)        // 6016
#define NOUT 1000
#define CAP 8192
#define NMS_T 0.7

// ---- workspace layout (bytes) ----
#define WS_HIST 0
#define WS_COUNTER 262144
#define WS_BINB 262148
#define WS_SELKEYS 262160
#define WS_SELIDX 327696
#define WS_BOXES 351696
#define WS_MASK 447952          // u64 maskT[NCH][NPAD]  (4524032 B)

// base anchors from generate_anchors() (numpy fp64, exact small values)
__device__ __constant__ float c_ax1[9] = {-84.f, -176.f, -360.f, -56.f, -120.f, -248.f, -36.f, -80.f, -168.f};
__device__ __constant__ float c_ay1[9] = {-40.f, -88.f, -184.f, -56.f, -120.f, -248.f, -80.f, -168.f, -344.f};
__device__ __constant__ float c_ax2[9] = {99.f, 191.f, 375.f, 71.f, 135.f, 263.f, 51.f, 95.f, 183.f};
__device__ __constant__ float c_ay2[9] = {55.f, 103.f, 199.f, 71.f, 135.f, 263.f, 95.f, 183.f, 359.f};

__device__ __forceinline__ unsigned score_key(float s) {
    unsigned u = __float_as_uint(s);
    return (u & 0x80000000u) ? ~u : (u | 0x80000000u);
}

// 64-lane OR-reduce via DPP (result valid in lane 63). OR is idempotent, so
// any unintended identity/zero source lanes in bcast modes are harmless.
__device__ __forceinline__ unsigned wave_or32(unsigned v) {
    v |= (unsigned)__builtin_amdgcn_update_dpp(0, (int)v, 0x111, 0xf, 0xf, true);  // row_shr:1
    v |= (unsigned)__builtin_amdgcn_update_dpp(0, (int)v, 0x112, 0xf, 0xf, true);  // row_shr:2
    v |= (unsigned)__builtin_amdgcn_update_dpp(0, (int)v, 0x114, 0xf, 0xf, true);  // row_shr:4
    v |= (unsigned)__builtin_amdgcn_update_dpp(0, (int)v, 0x118, 0xf, 0xf, true);  // row_shr:8
    v |= (unsigned)__builtin_amdgcn_update_dpp(0, (int)v, 0x142, 0xf, 0xf, true);  // row_bcast:15
    v |= (unsigned)__builtin_amdgcn_update_dpp(0, (int)v, 0x143, 0xf, 0xf, true);  // row_bcast:31
    return v;
}

// 1) histogram over top-16 bits of orderable score key
__global__ void k_hist(const float* __restrict__ scores, unsigned* __restrict__ hist) {
    int i = blockIdx.x * blockDim.x + threadIdx.x;
    if (i >= KK) return;
    int a = i % AA;
    int hw = i / AA;
    int h = hw >> 7;
    int w = hw & 127;
    float s = scores[(AA + a) * HWH + h * WW + w];
    atomicAdd(&hist[score_key(s) >> 16], 1u);
}

// 2) find largest bin B with count(key>>16 >= B) >= NSEL  (parallel suffix-scan)
__global__ __launch_bounds__(1024) void k_findbin(const unsigned* __restrict__ hist,
                                                  unsigned* __restrict__ binB) {
    __shared__ unsigned seg[1024];
    int t = threadIdx.x;
    unsigned local[64];
    unsigned s = 0;
#pragma unroll
    for (int k = 0; k < 64; ++k) { local[k] = hist[t * 64 + k]; s += local[k]; }
    seg[t] = s;
    __syncthreads();
    for (int off = 1; off < 1024; off <<= 1) {
        unsigned v = seg[t];
        unsigned add = (t + off < 1024) ? seg[t + off] : 0u;
        __syncthreads();
        seg[t] = v + add;
        __syncthreads();
    }
    unsigned above = (t + 1 < 1024) ? seg[t + 1] : 0u;
    if (above < NSEL && above + s >= NSEL) {
        unsigned acc = above;
#pragma unroll
        for (int b = 63; b >= 0; --b) {
            acc += local[b];
            if (acc >= NSEL) { *binB = (unsigned)(t * 64 + b); break; }
        }
    }
}

// 3) gather candidates (key>>16 >= B) as packed u64 (key desc, idx asc)
__global__ void k_gather(const float* __restrict__ scores, const unsigned* __restrict__ binB,
                         unsigned* __restrict__ counter, unsigned long long* __restrict__ selKeys) {
    int i = blockIdx.x * blockDim.x + threadIdx.x;
    if (i >= KK) return;
    int a = i % AA;
    int hw = i / AA;
    int h = hw >> 7;
    int w = hw & 127;
    float s = scores[(AA + a) * HWH + h * WW + w];
    unsigned key = score_key(s);
    if ((key >> 16) >= *binB) {
        unsigned pos = atomicAdd(counter, 1u);
        if (pos < CAP)
            selKeys[pos] = ((unsigned long long)key << 32) | (unsigned)(~(unsigned)i);
    }
}

// 4) one-block bitonic sort (descending) of 8192 u64; emit top-6000 indices
__global__ __launch_bounds__(1024) void k_sort(const unsigned* __restrict__ counter,
                                               const unsigned long long* __restrict__ selKeys,
                                               unsigned* __restrict__ selIdx) {
    __shared__ unsigned long long sk[CAP];
    int t = threadIdx.x;
    unsigned cnt = *counter;
    if (cnt > CAP) cnt = CAP;
    for (int p = t; p < CAP; p += 1024) sk[p] = (p < (int)cnt) ? selKeys[p] : 0ull;
    __syncthreads();
    for (unsigned size = 2; size <= CAP; size <<= 1) {
        for (unsigned stride = size >> 1; stride > 0; stride >>= 1) {
            for (unsigned p = (unsigned)t; p < CAP / 2; p += 1024) {
                unsigned i = 2u * p - (p & (stride - 1u));
                unsigned j = i + stride;
                bool up = (i & size) != 0;
                unsigned long long a = sk[i], b = sk[j];
                bool doswap = up ? (a > b) : (a < b);
                if (doswap) { sk[i] = b; sk[j] = a; }
            }
            __syncthreads();
        }
    }
    for (int p = t; p < NSEL; p += 1024)
        selIdx[p] = ~(unsigned)(sk[p] & 0xFFFFFFFFull);
}

// 5) decode+clip top-6000 boxes in fp64, store fp32
__global__ void k_decode(const float* __restrict__ bbox, const float* __restrict__ im_info,
                         const unsigned* __restrict__ selIdx, float4* __restrict__ boxes) {
    int r = blockIdx.x * blockDim.x + threadIdx.x;
    if (r >= NSEL) return;
    unsigned i = selIdx[r];
    int a = (int)(i % AA);
    int hw = (int)(i / AA);
    int h = hw >> 7;
    int w = hw & 127;
    double sx = 16.0 * w, sy = 16.0 * h;
    double ax1 = (double)c_ax1[a] + sx, ay1 = (double)c_ay1[a] + sy;
    double ax2 = (double)c_ax2[a] + sx, ay2 = (double)c_ay2[a] + sy;
    double aw = ax2 - ax1 + 1.0, ah = ay2 - ay1 + 1.0;
    double acx = ax1 + 0.5 * aw, acy = ay1 + 0.5 * ah;
    int base = h * WW + w;
    double d0 = (double)bbox[(4 * a + 0) * HWH + base];
    double d1 = (double)bbox[(4 * a + 1) * HWH + base];
    double d2 = (double)bbox[(4 * a + 2) * HWH + base];
    double d3 = (double)bbox[(4 * a + 3) * HWH + base];
    double pcx = d0 * aw + acx, pcy = d1 * ah + acy;
    double pw = exp(d2) * aw, ph = exp(d3) * ah;
    double xmax = (double)im_info[1] - 1.0, ymax = (double)im_info[0] - 1.0;
    double x1 = fmin(fmax(pcx - 0.5 * pw, 0.0), xmax);
    double y1 = fmin(fmax(pcy - 0.5 * ph, 0.0), ymax);
    double x2 = fmin(fmax(pcx + 0.5 * pw, 0.0), xmax);
    double y2 = fmin(fmax(pcy + 0.5 * ph, 0.0), ymax);
    boxes[r] = make_float4((float)x1, (float)y1, (float)x2, (float)y2);
}

// 6) suppression bitmask, TRANSPOSED layout: maskT[cc][gi] bit j =
//    (iou(gi, cc*64+j) > 0.7 && cc*64+j > gi). Coalesced 8B stores over gi.
__global__ __launch_bounds__(64) void k_mask(const float4* __restrict__ boxes,
                                             unsigned long long* __restrict__ maskT) {
    int rc = blockIdx.y, cc = blockIdx.x;
    if (cc < rc) return;
    __shared__ float4 cb[64];
    int t = threadIdx.x;
    cb[t] = boxes[cc * 64 + t];
    __syncthreads();
    int gi = rc * 64 + t;
    if (gi >= NSEL) return;
    float4 rb = boxes[gi];
    double rx1 = rb.x, ry1 = rb.y, rx2 = rb.z, ry2 = rb.w;
    double rarea = (rx2 - rx1 + 1.0) * (ry2 - ry1 + 1.0);
    unsigned long long bits = 0ull;
    for (int j = 0; j < 64; ++j) {
        int gj = cc * 64 + j;
        float4 c = cb[j];
        double iw = fmin(rx2, (double)c.z) - fmax(rx1, (double)c.x) + 1.0;
        double ih = fmin(ry2, (double)c.w) - fmax(ry1, (double)c.y) + 1.0;
        if (gj > gi && gj < NSEL && iw > 0.0 && ih > 0.0) {
            double inter = iw * ih;
            double carea = ((double)c.z - (double)c.x + 1.0) * ((double)c.w - (double)c.y + 1.0);
            double uni = rarea + carea - inter;
            if (inter > NMS_T * uni) bits |= (1ull << j);
        }
    }
    maskT[(size_t)cc * NPAD + gi] = bits;
}

// 7) greedy NMS reduce v3: no LDS tile; deep global prefetch into registers,
//    DPP wave-OR reduce, one barrier per chunk.
__global__ __launch_bounds__(1024) void k_nms(const unsigned long long* __restrict__ maskT,
                                              const float4* __restrict__ boxes,
                                              float4* __restrict__ out) {
    __shared__ unsigned long long removed[NCH];
    __shared__ unsigned long long aliveS[2];
    __shared__ unsigned scanBuf[1024];
    int t = threadIdx.x;
    int wave = t >> 6, lane = t & 63;
    unsigned long long A[6], B[6];
    unsigned long long dE = 0, dO = 0;

    if (t < NCH) removed[t] = (t == NCH - 1) ? 0xFFFF000000000000ull : 0ull;  // pad rows dead
    if (wave == 0) {
        dE = maskT[(size_t)0 * NPAD + 0 * 64 + lane];   // diag chunk 0
        dO = maskT[(size_t)1 * NPAD + 1 * 64 + lane];   // diag chunk 1
    }
#pragma unroll
    for (int q = 0; q < 6; ++q) {                        // OR-words for chunk 0
        int w = 1 + wave + (q << 4);
        A[q] = (w < NCH) ? maskT[(size_t)w * NPAD + lane] : 0ull;
    }
    __syncthreads();

    for (int c = 0; c < NCH; c += 2) {
        // ======== even chunk c (regs A; prefetch B for c+1) ========
#pragma unroll
        for (int q = 0; q < 6; ++q) {
            int w = c + 2 + wave + (q << 4);
            B[q] = (w < NCH) ? maskT[(size_t)w * NPAD + (c + 1) * 64 + lane] : 0ull;
        }
        if (wave == 0) {
            unsigned mlo = (unsigned)dE, mhi = (unsigned)(dE >> 32);
            if (c + 2 < NCH) dE = maskT[(size_t)(c + 2) * NPAD + (c + 2) * 64 + lane];
            unsigned long long rem = removed[c];
            unsigned alo = __builtin_amdgcn_readfirstlane((unsigned)(~rem));
            unsigned ahi = __builtin_amdgcn_readfirstlane((unsigned)((~rem) >> 32));
            unsigned long long alive = ((unsigned long long)ahi << 32) | alo;
            unsigned long long rest = alive;
            while (rest) {
                int i = __ffsll((long long)rest) - 1;
                i = __builtin_amdgcn_readfirstlane(i);
                unsigned long long mi =
                    ((unsigned long long)(unsigned)__builtin_amdgcn_readlane((int)mhi, i) << 32) |
                    (unsigned)__builtin_amdgcn_readlane((int)mlo, i);
                alive &= ~mi;
                rest &= ~mi;
                rest &= rest - 1;
            }
            if (lane == 0) { removed[c] = ~alive; aliveS[0] = alive; }
        }
        __syncthreads();
        {
            unsigned long long alive = aliveS[0];
            unsigned long long sel = 0ull - ((alive >> lane) & 1ull);
#pragma unroll
            for (int q = 0; q < 6; ++q) {
                int w = c + 1 + wave + (q << 4);
                if (w < NCH) {
                    unsigned long long v = A[q] & sel;
                    unsigned lo = wave_or32((unsigned)v);
                    unsigned hi = wave_or32((unsigned)(v >> 32));
                    if (lane == 63) removed[w] |= ((unsigned long long)hi << 32) | lo;
                }
            }
        }
        // ======== odd chunk c+1 (regs B; prefetch A for c+2) ========
#pragma unroll
        for (int q = 0; q < 6; ++q) {
            int w = c + 3 + wave + (q << 4);
            A[q] = (w < NCH) ? maskT[(size_t)w * NPAD + (c + 2) * 64 + lane] : 0ull;
        }
        if (wave == 0) {
            unsigned mlo = (unsigned)dO, mhi = (unsigned)(dO >> 32);
            if (c + 3 < NCH) dO = maskT[(size_t)(c + 3) * NPAD + (c + 3) * 64 + lane];
            unsigned long long rem = removed[c + 1];
            unsigned alo = __builtin_amdgcn_readfirstlane((unsigned)(~rem));
            unsigned ahi = __builtin_amdgcn_readfirstlane((unsigned)((~rem) >> 32));
            unsigned long long alive = ((unsigned long long)ahi << 32) | alo;
            unsigned long long rest = alive;
            while (rest) {
                int i = __ffsll((long long)rest) - 1;
                i = __builtin_amdgcn_readfirstlane(i);
                unsigned long long mi =
                    ((unsigned long long)(unsigned)__builtin_amdgcn_readlane((int)mhi, i) << 32) |
                    (unsigned)__builtin_amdgcn_readlane((int)mlo, i);
                alive &= ~mi;
                rest &= ~mi;
                rest &= rest - 1;
            }
            if (lane == 0) { removed[c + 1] = ~alive; aliveS[1] = alive; }
        }
        __syncthreads();
        {
            unsigned long long alive = aliveS[1];
            unsigned long long sel = 0ull - ((alive >> lane) & 1ull);
#pragma unroll
            for (int q = 0; q < 6; ++q) {
                int w = c + 2 + wave + (q << 4);
                if (w < NCH) {
                    unsigned long long v = B[q] & sel;
                    unsigned lo = wave_or32((unsigned)v);
                    unsigned hi = wave_or32((unsigned)(v >> 32));
                    if (lane == 63) removed[w] |= ((unsigned long long)hi << 32) | lo;
                }
            }
        }
    }
    __syncthreads();

    // stable compaction: kept (index asc) then suppressed (index asc), take first 1000
    int base = t * 6;
    unsigned cnt = 0, keepbits = 0;
    for (int q = 0; q < 6; ++q) {
        int i = base + q;
        if (i < NSEL) {
            bool kp = !((removed[i >> 6] >> (i & 63)) & 1ull);
            if (kp) { cnt++; keepbits |= (1u << q); }
        }
    }
    scanBuf[t] = cnt;
    __syncthreads();
    for (int off = 1; off < 1024; off <<= 1) {
        unsigned v = scanBuf[t];
        unsigned add = (t >= off) ? scanBuf[t - off] : 0u;
        __syncthreads();
        scanBuf[t] = v + add;
        __syncthreads();
    }
    unsigned incl = scanBuf[t];
    unsigned NK = scanBuf[1023];
    unsigned kpos = incl - cnt;
    for (int q = 0; q < 6; ++q) {
        int i = base + q;
        if (i < NSEL) {
            bool kp = (keepbits >> q) & 1u;
            unsigned pos = kp ? kpos : (NK + (unsigned)i - kpos);
            if (kp) kpos++;
            if (pos < NOUT) out[pos] = boxes[i];
        }
    }
}

extern "C" void kernel_launch(void* const* d_in, const int* in_sizes, int n_in,
                              void* d_out, int out_size, void* d_ws, size_t ws_size,
                              hipStream_t stream) {
    const float* scores = (const float*)d_in[0];
    const float* bbox = (const float*)d_in[1];
    const float* im_info = (const float*)d_in[2];
    char* ws = (char*)d_ws;

    unsigned* hist = (unsigned*)(ws + WS_HIST);
    unsigned* counter = (unsigned*)(ws + WS_COUNTER);
    unsigned* binB = (unsigned*)(ws + WS_BINB);
    unsigned long long* selKeys = (unsigned long long*)(ws + WS_SELKEYS);
    unsigned* selIdx = (unsigned*)(ws + WS_SELIDX);
    float4* boxes = (float4*)(ws + WS_BOXES);
    unsigned long long* maskT = (unsigned long long*)(ws + WS_MASK);
    float4* out = (float4*)d_out;

    hipMemsetAsync(ws, 0, WS_BINB + 4, stream);

    k_hist<<<(KK + 255) / 256, 256, 0, stream>>>(scores, hist);
    k_findbin<<<1, 1024, 0, stream>>>(hist, binB);
    k_gather<<<(KK + 255) / 256, 256, 0, stream>>>(scores, binB, counter, selKeys);
    k_sort<<<1, 1024, 0, stream>>>(counter, selKeys, selIdx);
    k_decode<<<(NSEL + 255) / 256, 256, 0, stream>>>(bbox, im_info, selIdx, boxes);
    k_mask<<<dim3(NCH, NCH), 64, 0, stream>>>(boxes, maskT);
    k_nms<<<1, 1024, 0, stream>>>(maskT, boxes, out);
}